// Round 2
// baseline (1013.186 us; speedup 1.0000x reference)
//
#include <hip/hip_runtime.h>
#include <hip/hip_bf16.h>
#include <stdint.h>

// DeepseekCompressor: out = scatter(slots, [x@W0^T, x@W1^T + ape[pos%128]]) over copy(cache)
// Round 5 changes vs round 4:
//  - prep ELIMINATED on the main path: the 256x256 GEMM now reg-stages A and B
//    directly from fp32 (global->reg one K-tile ahead, cvt to bf16, ds_write to
//    swizzled LDS dest; source loads stay linear/coalesced). Saves ~940 MB of
//    HBM round-trip (x fp32 read + xb write + xb re-read collapses to one fp32 read).
//  - cache copy (flags-gated) fused into the GEMM tail (grid-stride).
//  - one barrier per K-tile (write-own-buf after compute; entry barrier covers WAR).
//  - main path kernels: memset(flags 32KB) + set_flags + gemm_fused_256.
//  - old prep + 128^2 bf16 + f32 kernels kept as fallbacks for odd shapes/ws.

typedef short  bf16x8 __attribute__((ext_vector_type(8)));
typedef float  f32x4  __attribute__((ext_vector_type(4)));

#define BM 128
#define BN 128
#define BK 32
#define NT 256

// 256-squared fused pipeline geometry
#define GBM 256
#define GBN 256
#define GBK 64
#define GNT 512

__device__ __forceinline__ uint32_t pack_bf16x2(float lo, float hi) {
    uint32_t a = __float_as_uint(lo);
    uint32_t b = __float_as_uint(hi);
    a += 0x7fffu + ((a >> 16) & 1u);
    b += 0x7fffu + ((b >> 16) & 1u);
    return (a >> 16) | (b & 0xffff0000u);
}

__device__ __forceinline__ void gload_lds16(const uint16_t* g, uint16_t* l) {
    __builtin_amdgcn_global_load_lds(
        (const __attribute__((address_space(1))) uint32_t*)g,
        (__attribute__((address_space(3))) uint32_t*)l,
        16, 0, 0);
}

// ---------------- flag mapped slots ----------------
__global__ void set_flags(const int* __restrict__ slots, uint8_t* __restrict__ flags,
                          int num_tokens, int num_slots) {
    const int i = blockIdx.x * blockDim.x + threadIdx.x;
    if (i < num_tokens) {
        const int s = slots[i];
        if (s >= 0 && s < num_slots) flags[s] = 1;
    }
}

// ---------------- v3: fused 256x256 BK=64 reg-staged GEMM + ape + scatter + copy ---
// LDS: 2 buffers x (A 256x64 + B 256x64) bf16 = 128 KiB. 1 block/CU, 8 waves.
// Staging: thread t owns rows {q*64 + (t>>3)}, chunk c = t&7 (16B bf16 / 32B fp32).
// LDS[row][chunk] holds G[row][chunk ^ (row&7)]  (dest-side XOR swizzle; read side
// uses the same XOR — identical mapping to the round-4 kernel that passed).
__global__ __launch_bounds__(GNT, 2)
void gemm_fused_256(const float* __restrict__ X, const float* __restrict__ Wm,
                    const float* __restrict__ ape, const int* __restrict__ positions,
                    const int* __restrict__ slots, const float4* __restrict__ cache4,
                    const uint8_t* __restrict__ flags, float* __restrict__ out,
                    int K, int D, int CR, int num_slots, int n_tiles_m, int n_tiles_n)
{
    __shared__ uint16_t lds[2 * 2 * GBM * GBK];   // [buf][A,B][256*64] bf16 = 128 KiB

    const int t    = threadIdx.x;
    const int lane = t & 63;
    const int wid  = t >> 6;          // 0..7
    const int wr   = wid >> 2;        // 0..1  (m-half)
    const int wc   = wid & 3;         // 0..3  (n-quarter)
    const int fr   = lane & 15;
    const int fc4  = lane >> 4;       // 0..3

    // T1: XCD-grouped mapping (8 consecutive tile_m strips per XCD).
    const int nblk = n_tiles_m * n_tiles_n;
    int tidx = blockIdx.x;
    if ((nblk & 7) == 0) {
        const int per = nblk >> 3;
        tidx = (tidx & 7) * per + (tidx >> 3);
    }
    const int tile_m = tidx / n_tiles_n;
    const int tile_n = tidx % n_tiles_n;

    // staging addresses
    const int srow = t >> 3;                        // 0..63
    const int c    = t & 7;                         // 16B-chunk index
    const int swzc = c ^ (srow & 7);                // dest chunk (row&7 invariant per q)
    const float* gA = X  + (size_t)(tile_m * GBM + srow) * K + c * 8;
    const float* gB = Wm + (size_t)(tile_n * GBN + srow) * K + c * 8;
    uint16_t* const wA0 = lds + srow * GBK + swzc * 8;   // + q*64*GBK + buf offset

    // frag ds_read offsets (unchanged from round 4): chunk (h*4+fc4) ^ (fr&7)
    const int c0 = (fc4 ^ (fr & 7)) * 8;
    const int c1 = ((4 + fc4) ^ (fr & 7)) * 8;
    const int arow0 = (wr * 128 + fr) * GBK;
    const int brow0 = (wc * 64 + fr) * GBK;

    float4 ra[4][2], rb[4][2];   // staged fp32 for the NEXT K-tile (64 VGPR)

    f32x4 acc[8][4];
    #pragma unroll
    for (int i = 0; i < 8; i++)
        #pragma unroll
        for (int j = 0; j < 4; j++)
            acc[i][j] = f32x4{0.f, 0.f, 0.f, 0.f};

    const int nkt = K / GBK;

#define LOADT(kt_) do {                                                       \
    const size_t ko_ = (size_t)(kt_) * GBK;                                   \
    _Pragma("unroll")                                                         \
    for (int q_ = 0; q_ < 4; q_++) {                                          \
        ra[q_][0] = *(const float4*)(gA + ko_ + (size_t)q_ * 64 * K);         \
        ra[q_][1] = *(const float4*)(gA + ko_ + (size_t)q_ * 64 * K + 4);     \
        rb[q_][0] = *(const float4*)(gB + ko_ + (size_t)q_ * 64 * K);         \
        rb[q_][1] = *(const float4*)(gB + ko_ + (size_t)q_ * 64 * K + 4);     \
    }                                                                         \
} while (0)

// cvt + ds_write the staged regs into buffer buf_; per-q write-then-(re)load
// keeps register lifetimes short (WAR recycling of ra/rb).
#define WRITET(buf_) do {                                                     \
    uint16_t* bA_ = wA0 + (buf_) * (2 * GBM * GBK);                           \
    uint16_t* bB_ = bA_ + GBM * GBK;                                          \
    _Pragma("unroll")                                                         \
    for (int q_ = 0; q_ < 4; q_++) {                                          \
        uint4 oa_, ob_;                                                       \
        oa_.x = pack_bf16x2(ra[q_][0].x, ra[q_][0].y);                        \
        oa_.y = pack_bf16x2(ra[q_][0].z, ra[q_][0].w);                        \
        oa_.z = pack_bf16x2(ra[q_][1].x, ra[q_][1].y);                        \
        oa_.w = pack_bf16x2(ra[q_][1].z, ra[q_][1].w);                        \
        *(uint4*)(bA_ + q_ * 64 * GBK) = oa_;                                 \
        ob_.x = pack_bf16x2(rb[q_][0].x, rb[q_][0].y);                        \
        ob_.y = pack_bf16x2(rb[q_][0].z, rb[q_][0].w);                        \
        ob_.z = pack_bf16x2(rb[q_][1].x, rb[q_][1].y);                        \
        ob_.w = pack_bf16x2(rb[q_][1].z, rb[q_][1].w);                        \
        *(uint4*)(bB_ + q_ * 64 * GBK) = ob_;                                 \
    }                                                                         \
} while (0)

    // prologue: stage tile 0, issue loads for tile 1
    LOADT(0);
    WRITET(0);                         // compiler inserts the vmcnt for ra/rb uses
    if (nkt > 1) LOADT(1);
    asm volatile("s_waitcnt lgkmcnt(0)" ::: "memory");
    __builtin_amdgcn_sched_barrier(0);
    __builtin_amdgcn_s_barrier();
    asm volatile("" ::: "memory");
    __builtin_amdgcn_sched_barrier(0);

    for (int kt = 0; kt < nkt; ++kt) {
        const int cur = kt & 1;
        const uint16_t* A = lds + cur * (2 * GBM * GBK);
        const uint16_t* B = A + GBM * GBK;

        #pragma unroll
        for (int h = 0; h < 2; ++h) {
            const int cN = h ? c1 : c0;
            bf16x8 bfr[4];
            #pragma unroll
            for (int j = 0; j < 4; ++j)
                bfr[j] = *(const bf16x8*)(B + brow0 + j * (16 * GBK) + cN);
            #pragma unroll
            for (int mh = 0; mh < 2; ++mh) {
                bf16x8 afr[4];
                #pragma unroll
                for (int i = 0; i < 4; ++i)
                    afr[i] = *(const bf16x8*)(A + arow0 + mh * (64 * GBK) + i * (16 * GBK) + cN);
                __builtin_amdgcn_s_setprio(1);   // T5
                #pragma unroll
                for (int i = 0; i < 4; ++i)
                    #pragma unroll
                    for (int j = 0; j < 4; ++j)
                        acc[mh * 4 + i][j] = __builtin_amdgcn_mfma_f32_16x16x32_bf16(
                            afr[i], bfr[j], acc[mh * 4 + i][j], 0, 0, 0);
                __builtin_amdgcn_s_setprio(0);
            }
        }

        if (kt + 1 < nkt) {
            __builtin_amdgcn_sched_barrier(0);   // keep staging after compute
            WRITET(cur ^ 1);                     // buf[nxt] free since entry barrier
            if (kt + 2 < nkt) LOADT(kt + 2);     // ~2500 cy of cover before use
            asm volatile("s_waitcnt lgkmcnt(0)" ::: "memory");
            __builtin_amdgcn_sched_barrier(0);
            __builtin_amdgcn_s_barrier();        // buf[nxt] now visible to all
            asm volatile("" ::: "memory");
            __builtin_amdgcn_sched_barrier(0);
        }
    }
#undef LOADT
#undef WRITET

    // epilogue: C/D layout col=lane&15, row=(lane>>4)*4+reg (m89-verified)
    const int D2 = 2 * D;
    const int mbase = tile_m * GBM + wr * 128 + fc4 * 4;
    const int nbase = tile_n * GBN + wc * 64 + fr;
    #pragma unroll
    for (int ai = 0; ai < 8; ++ai) {
        #pragma unroll
        for (int r = 0; r < 4; ++r) {
            const int token = mbase + ai * 16 + r;
            const int slot  = slots[token];
            if (slot < 0 || slot >= num_slots) continue;
            int p = positions[token];
            p = (CR & (CR - 1)) ? (p % CR) : (p & (CR - 1));
            const float* aperow = ape + (size_t)p * D;
            float* orow = out + (size_t)slot * D2;
            #pragma unroll
            for (int j = 0; j < 4; ++j) {
                const int col = nbase + j * 16;
                float v = acc[ai][j][r];
                if (col >= D) v += aperow[col - D];
                orow[col] = v;
            }
        }
    }

    // fused cache copy: rows not touched by the scatter (flags==0)
    float4* out4 = (float4*)out;
    const int rowlen4 = D2 >> 2;
    if ((rowlen4 & (rowlen4 - 1)) == 0) {
        int sh = 0;
        while ((1 << sh) < rowlen4) ++sh;
        const long total4 = (long)num_slots << sh;
        for (long i = (long)blockIdx.x * GNT + t; i < total4; i += (long)gridDim.x * GNT)
            if (!flags[i >> sh]) out4[i] = cache4[i];
    } else {
        for (int s = blockIdx.x; s < num_slots; s += gridDim.x) {
            if (flags[s]) continue;
            const float4* src = cache4 + (size_t)s * rowlen4;
            float4* dst = out4 + (size_t)s * rowlen4;
            for (int j = t; j < rowlen4; j += GNT) dst[j] = src[j];
        }
    }
}

// ---------------- fallback prep: cache copy (skip overwritten) + cvt x + cvt W ----
__global__ void prep(const float4* __restrict__ cache, float4* __restrict__ out,
                     const uint8_t* __restrict__ flags,
                     const float4* __restrict__ x, uint4* __restrict__ xb,
                     const float4* __restrict__ w, uint4* __restrict__ wb,
                     int n_c4, int nx8, int nw8) {
    const int i = blockIdx.x * blockDim.x + threadIdx.x;
    if (i < n_c4) {
        if (!flags[i >> 8]) out[i] = cache[i];
    } else if (i < n_c4 + nx8) {
        const int j = i - n_c4;
        const float4 a = x[2 * j];
        const float4 b = x[2 * j + 1];
        uint4 o;
        o.x = pack_bf16x2(a.x, a.y);
        o.y = pack_bf16x2(a.z, a.w);
        o.z = pack_bf16x2(b.x, b.y);
        o.w = pack_bf16x2(b.z, b.w);
        xb[j] = o;
    } else if (i < n_c4 + nx8 + nw8) {
        const int j = i - n_c4 - nx8;
        const float4 a = w[2 * j];
        const float4 b = w[2 * j + 1];
        uint4 o;
        o.x = pack_bf16x2(a.x, a.y);
        o.y = pack_bf16x2(a.z, a.w);
        o.z = pack_bf16x2(b.x, b.y);
        o.w = pack_bf16x2(b.z, b.w);
        wb[j] = o;
    }
}

// ---------------- fallback 128x128 bf16 GEMM (non-divisible shapes) ----------
__global__ __launch_bounds__(NT, 4)
void gemm_bf16_scatter(const uint16_t* __restrict__ XB, const uint16_t* __restrict__ WB,
                       const float* __restrict__ ape, const int* __restrict__ positions,
                       const int* __restrict__ slots, float* __restrict__ out,
                       int K, int D, int CR, int num_slots, int n_tiles_m)
{
    __shared__ uint16_t ldsA[BM * BK];
    __shared__ uint16_t ldsB[BN * BK];

    const int tile_m = blockIdx.x % n_tiles_m;
    const int tile_n = blockIdx.x / n_tiles_m;
    const int t    = threadIdx.x;
    const int lane = t & 63;
    const int wid  = t >> 6;
    const int wm   = (wid >> 1) * 64;
    const int wn   = (wid & 1) * 64;
    const int fr   = lane & 15;
    const int fc   = lane >> 4;
    const int swz  = (fc ^ ((fr >> 1) & 3)) << 3;

    const int p0 = t, p1 = t + NT;
    const int r0 = p0 >> 2, cc0 = (p0 & 3) ^ ((r0 >> 1) & 3);
    const int r1 = p1 >> 2, cc1 = (p1 & 3) ^ ((r1 >> 1) & 3);

    const uint16_t* gA0 = XB + (size_t)(tile_m * BM + r0) * K + cc0 * 8;
    const uint16_t* gA1 = XB + (size_t)(tile_m * BM + r1) * K + cc1 * 8;
    const uint16_t* gB0 = WB + (size_t)(tile_n * BN + r0) * K + cc0 * 8;
    const uint16_t* gB1 = WB + (size_t)(tile_n * BN + r1) * K + cc1 * 8;
    uint16_t* lA0 = &ldsA[p0 * 8];
    uint16_t* lA1 = &ldsA[p1 * 8];
    uint16_t* lB0 = &ldsB[p0 * 8];
    uint16_t* lB1 = &ldsB[p1 * 8];

    f32x4 acc[4][4];
    #pragma unroll
    for (int i = 0; i < 4; i++)
        #pragma unroll
        for (int j = 0; j < 4; j++)
            acc[i][j] = f32x4{0.f, 0.f, 0.f, 0.f};

    for (int k0 = 0; k0 < K; k0 += BK) {
        gload_lds16(gA0 + k0, lA0);
        gload_lds16(gA1 + k0, lA1);
        gload_lds16(gB0 + k0, lB0);
        gload_lds16(gB1 + k0, lB1);
        __syncthreads();

        bf16x8 af[4], bfrag[4];
        #pragma unroll
        for (int i = 0; i < 4; i++)
            af[i] = *(const bf16x8*)&ldsA[(wm + i * 16 + fr) * BK + swz];
        #pragma unroll
        for (int j = 0; j < 4; j++)
            bfrag[j] = *(const bf16x8*)&ldsB[(wn + j * 16 + fr) * BK + swz];

        #pragma unroll
        for (int i = 0; i < 4; i++)
            #pragma unroll
            for (int j = 0; j < 4; j++)
                acc[i][j] = __builtin_amdgcn_mfma_f32_16x16x32_bf16(af[i], bfrag[j], acc[i][j], 0, 0, 0);
        __syncthreads();
    }

    const int D2 = 2 * D;
    #pragma unroll
    for (int i = 0; i < 4; i++) {
        #pragma unroll
        for (int r = 0; r < 4; r++) {
            const int token = tile_m * BM + wm + i * 16 + fc * 4 + r;
            const int slot  = slots[token];
            if (slot < 0 || slot >= num_slots) continue;
            const int p = positions[token] % CR;
            const float* aperow = ape + (size_t)p * D;
            float* orow = out + (size_t)slot * D2;
            #pragma unroll
            for (int j = 0; j < 4; j++) {
                const int col = tile_n * BN + wn + j * 16 + fr;
                float v = acc[i][j][r];
                if (col >= D) v += aperow[col - D];
                orow[col] = v;
            }
        }
    }
}

// ---------------- fallback (ws too small): round-1 fp32-staging GEMM ----------------
__global__ void copy_cache(const float4* __restrict__ src, float4* __restrict__ dst, int n4) {
    const int i = blockIdx.x * blockDim.x + threadIdx.x;
    if (i < n4) dst[i] = src[i];
}

__device__ __forceinline__ int lds_idx_f(int row, int chunk) {
    return row * BK + ((chunk ^ ((row >> 1) & 3)) << 3);
}

__global__ __launch_bounds__(NT, 2)
void gemm_scatter_f32(const float* __restrict__ X, const float* __restrict__ Wm,
                      const float* __restrict__ ape, const int* __restrict__ positions,
                      const int* __restrict__ slots, float* __restrict__ out,
                      int K, int D, int CR, int num_slots, int n_tiles_n)
{
    __shared__ uint16_t ldsA[BM * BK];
    __shared__ uint16_t ldsB[BN * BK];

    const int tile_m = blockIdx.x / n_tiles_n;
    const int tile_n = blockIdx.x % n_tiles_n;
    const int t    = threadIdx.x;
    const int lane = t & 63;
    const int wid  = t >> 6;
    const int wm   = (wid >> 1) * 64;
    const int wn   = (wid & 1) * 64;
    const int fr   = lane & 15;
    const int fc   = lane >> 4;
    const int swz  = fc ^ ((fr >> 1) & 3);

    const float* Abase = X  + (size_t)(tile_m * BM) * K;
    const float* Bbase = Wm + (size_t)(tile_n * BN) * K;

    f32x4 acc[4][4];
    #pragma unroll
    for (int i = 0; i < 4; i++)
        #pragma unroll
        for (int j = 0; j < 4; j++)
            acc[i][j] = f32x4{0.f, 0.f, 0.f, 0.f};

    for (int k0 = 0; k0 < K; k0 += BK) {
        #pragma unroll
        for (int i = 0; i < 4; i++) {
            const int lin = t + i * NT;
            const int row = lin >> 3;
            const int c4  = lin & 7;
            const int half = c4 & 1;
            const int sidx = lds_idx_f(row, c4 >> 1) + half * 4;

            const float4 va = *(const float4*)(Abase + (size_t)row * K + k0 + c4 * 4);
            uint2 pa; pa.x = pack_bf16x2(va.x, va.y); pa.y = pack_bf16x2(va.z, va.w);
            *(uint2*)&ldsA[sidx] = pa;

            const float4 vb = *(const float4*)(Bbase + (size_t)row * K + k0 + c4 * 4);
            uint2 pb; pb.x = pack_bf16x2(vb.x, vb.y); pb.y = pack_bf16x2(vb.z, vb.w);
            *(uint2*)&ldsB[sidx] = pb;
        }
        __syncthreads();

        bf16x8 af[4], bfrag[4];
        #pragma unroll
        for (int i = 0; i < 4; i++)
            af[i] = *(const bf16x8*)&ldsA[(wm + i * 16 + fr) * BK + (swz << 3)];
        #pragma unroll
        for (int j = 0; j < 4; j++)
            bfrag[j] = *(const bf16x8*)&ldsB[(wn + j * 16 + fr) * BK + (swz << 3)];

        #pragma unroll
        for (int i = 0; i < 4; i++)
            #pragma unroll
            for (int j = 0; j < 4; j++)
                acc[i][j] = __builtin_amdgcn_mfma_f32_16x16x32_bf16(af[i], bfrag[j], acc[i][j], 0, 0, 0);
        __syncthreads();
    }

    const int D2 = 2 * D;
    #pragma unroll
    for (int i = 0; i < 4; i++) {
        #pragma unroll
        for (int r = 0; r < 4; r++) {
            const int token = tile_m * BM + wm + i * 16 + fc * 4 + r;
            const int slot  = slots[token];
            if (slot < 0 || slot >= num_slots) continue;
            const int p = positions[token] % CR;
            const float* aperow = ape + (size_t)p * D;
            float* orow = out + (size_t)slot * D2;
            #pragma unroll
            for (int j = 0; j < 4; j++) {
                const int col = tile_n * BN + wn + j * 16 + fr;
                float v = acc[i][j][r];
                if (col >= D) v += aperow[col - D];
                orow[col] = v;
            }
        }
    }
}

extern "C" void kernel_launch(void* const* d_in, const int* in_sizes, int n_in,
                              void* d_out, int out_size, void* d_ws, size_t ws_size,
                              hipStream_t stream) {
    const float* x         = (const float*)d_in[0];
    const float* W         = (const float*)d_in[1];
    const float* ape       = (const float*)d_in[2];
    const float* cache     = (const float*)d_in[3];
    const int*   positions = (const int*)d_in[4];
    const int*   slots     = (const int*)d_in[5];
    float* out = (float*)d_out;

    const int num_tokens = in_sizes[4];
    const int hidden     = in_sizes[0] / num_tokens;   // 7168
    const int D2         = in_sizes[1] / hidden;       // 1024
    const int D          = D2 / 2;                     // 512
    const int CR         = in_sizes[2] / D;            // 128
    const int num_slots  = in_sizes[3] / D2;           // 32768

    const int n_tiles_m = num_tokens / BM;   // 128
    const int n_tiles_n = D2 / BN;           // 8

    const size_t nx = (size_t)in_sizes[0];
    const size_t nw = (size_t)in_sizes[1];
    const size_t need_old = (nx + nw) * sizeof(uint16_t) + (size_t)num_slots;

    const bool div256 = (num_tokens % GBM == 0) && (D2 % GBN == 0) && (hidden % GBK == 0);

    if (div256 && ws_size >= (size_t)num_slots) {
        // main path: no prep — GEMM reg-stages fp32 directly and copies cache in-tail
        uint8_t* flags = (uint8_t*)d_ws;
        hipMemsetAsync(flags, 0, num_slots, stream);
        set_flags<<<(num_tokens + 255) / 256, 256, 0, stream>>>(slots, flags, num_tokens, num_slots);

        const int tm = num_tokens / GBM;   // 64
        const int tn = D2 / GBN;           // 4
        gemm_fused_256<<<tm * tn, GNT, 0, stream>>>(
            x, W, ape, positions, slots, (const float4*)cache, flags, out,
            hidden, D, CR, num_slots, tm, tn);
    } else if (ws_size >= need_old) {
        uint16_t* xb = (uint16_t*)d_ws;
        uint16_t* wb = xb + nx;
        uint8_t* flags = (uint8_t*)(wb + nw);

        hipMemsetAsync(flags, 0, num_slots, stream);
        set_flags<<<(num_tokens + 255) / 256, 256, 0, stream>>>(slots, flags, num_tokens, num_slots);

        const int n_c4 = out_size / 4;
        const int nx8  = (int)(nx / 8);
        const int nw8  = (int)(nw / 8);
        const int total = n_c4 + nx8 + nw8;
        prep<<<(total + 255) / 256, 256, 0, stream>>>(
            (const float4*)cache, (float4*)out, flags,
            (const float4*)x, (uint4*)xb, (const float4*)W, (uint4*)wb,
            n_c4, nx8, nw8);

        gemm_bf16_scatter<<<n_tiles_m * n_tiles_n, NT, 0, stream>>>(
            xb, wb, ape, positions, slots, out, hidden, D, CR, num_slots, n_tiles_m);
    } else {
        const int n4 = out_size / 4;
        copy_cache<<<(n4 + 255) / 256, 256, 0, stream>>>((const float4*)cache, (float4*)out, n4);
        gemm_scatter_f32<<<n_tiles_m * n_tiles_n, NT, 0, stream>>>(
            x, W, ape, positions, slots, out, hidden, D, CR, num_slots, n_tiles_n);
    }
}

// Round 3
// 983.634 us; speedup vs baseline: 1.0300x; 1.0300x over previous
//
#include <hip/hip_runtime.h>
#include <hip/hip_bf16.h>
#include <stdint.h>

// DeepseekCompressor: out = scatter(slots, [x@W0^T, x@W1^T + ape[pos%128]]) over copy(cache)
// Round 6 changes vs round 5 (round-5 post-mortem: emulated bf16 pack = 5 VALU/2 floats
// -> ~150us of staging VALU serialized into a lockstep stage phase; MfmaUtil 21%):
//  - v_cvt_pk_bf16_f32 inline asm for all staging conversion (1 instr / 2 floats, RNE).
//  - stage (cvt + ds_write of next tile + global-load issue for tile kt+2) moved
//    BEFORE the MFMA phase with no sched fence between them: compiler interleaves
//    staging VALU/DS-writes with MFMA (separate pipes), nothing lockstep-exposed.
//  - sync skeleton = round-4's proven one: lgkmcnt(0) + raw s_barrier once per K-tile;
//    global loads stay in flight across barriers (issued 1 iteration ahead).
//  - LDS image + frag-read swizzle byte-identical to the round-4 kernel that passed.

typedef short  bf16x8 __attribute__((ext_vector_type(8)));
typedef float  f32x4  __attribute__((ext_vector_type(4)));

#define BM 128
#define BN 128
#define BK 32
#define NT 256

// fused 256-squared pipeline geometry
#define GBM 256
#define GBN 256
#define GBK 64
#define GNT 512

__device__ __forceinline__ uint32_t pack_bf16x2(float lo, float hi) {
    uint32_t a = __float_as_uint(lo);
    uint32_t b = __float_as_uint(hi);
    a += 0x7fffu + ((a >> 16) & 1u);
    b += 0x7fffu + ((b >> 16) & 1u);
    return (a >> 16) | (b & 0xffff0000u);
}

// HW packed cvt, RNE (same rounding as pack_bf16x2). lo -> D[15:0], hi -> D[31:16].
__device__ __forceinline__ uint32_t cvtpk(float lo, float hi) {
    uint32_t r;
    asm("v_cvt_pk_bf16_f32 %0, %1, %2" : "=v"(r) : "v"(lo), "v"(hi));
    return r;
}

__device__ __forceinline__ void gload_lds16(const uint16_t* g, uint16_t* l) {
    __builtin_amdgcn_global_load_lds(
        (const __attribute__((address_space(1))) uint32_t*)g,
        (__attribute__((address_space(3))) uint32_t*)l,
        16, 0, 0);
}

// ---------------- flag mapped slots ----------------
__global__ void set_flags(const int* __restrict__ slots, uint8_t* __restrict__ flags,
                          int num_tokens, int num_slots) {
    const int i = blockIdx.x * blockDim.x + threadIdx.x;
    if (i < num_tokens) {
        const int s = slots[i];
        if (s >= 0 && s < num_slots) flags[s] = 1;
    }
}

// ---------------- v4: fused 256x256 BK=64 GEMM, fp32 in, cvt_pk staging ----------
// LDS: 2 x (A 256x64 + B 256x64) bf16 = 128 KiB. 1 block/CU, 8 waves (2x4).
// Per K-tile, thread t stages 4 A-chunks + 4 B-chunks (16B bf16 each, from 32B fp32):
//   row = (t>>3)+q*64, dest chunk = t&7, source chunk = (t&7)^(row&7) (pre-swizzled
//   source, linear dest -> LDS[row][c] = G[row][c^(row&7)], same image as round 4).
// Loads for tile kt+2 are issued in iter kt, consumed (cvt+ds_write) in iter kt+1:
//   ~1 full iteration of cover; no vmcnt drain in the loop (compiler counts them).
__global__ __launch_bounds__(GNT, 2)
void gemm_fused2_256(const float* __restrict__ X, const float* __restrict__ Wm,
                     const float* __restrict__ ape, const int* __restrict__ positions,
                     const int* __restrict__ slots, const float4* __restrict__ cache4,
                     const uint8_t* __restrict__ flags, float* __restrict__ out,
                     int K, int D, int CR, int num_slots, int n_tiles_m, int n_tiles_n)
{
    __shared__ uint16_t lds[2 * 2 * GBM * GBK];   // [buf][A,B][256*64] bf16 = 128 KiB

    const int t    = threadIdx.x;
    const int lane = t & 63;
    const int wid  = t >> 6;          // 0..7
    const int wr   = wid >> 2;        // 0..1  (m-half)
    const int wc   = wid & 3;         // 0..3  (n-quarter)
    const int fr   = lane & 15;
    const int fc4  = lane >> 4;       // 0..3

    // T1: XCD-grouped mapping (8 consecutive tile_m strips per XCD chunk).
    const int nblk = n_tiles_m * n_tiles_n;
    int tidx = blockIdx.x;
    if ((nblk & 7) == 0) {
        const int per = nblk >> 3;
        tidx = (tidx & 7) * per + (tidx >> 3);
    }
    const int tile_m = tidx / n_tiles_n;
    const int tile_n = tidx % n_tiles_n;

    // staging constants
    const int srow = t >> 3;                        // 0..63
    const int scs  = ((t & 7) ^ (srow & 7)) * 8;    // source elem offset (swizzled)
    const float* pA[4];
    const float* pB[4];
    #pragma unroll
    for (int q = 0; q < 4; ++q) {
        pA[q] = X  + (size_t)(tile_m * GBM + srow + q * 64) * K + scs;
        pB[q] = Wm + (size_t)(tile_n * GBN + srow + q * 64) * K + scs;
    }
    const int dst0 = t * 8;                         // uint16 units; +q*4096 per q

    // frag ds_read offsets (identical to round-4): chunk (h*4+fc4) ^ (fr&7)
    const int c0 = (fc4 ^ (fr & 7)) * 8;
    const int c1 = ((4 + fc4) ^ (fr & 7)) * 8;
    const int arow0 = (wr * 128 + fr) * GBK;
    const int brow0 = (wc * 64 + fr) * GBK;

    float4 ra[4][2], rb[4][2];        // fp32 for the NEXT tile to be written

    f32x4 acc[8][4];
    #pragma unroll
    for (int i = 0; i < 8; i++)
        #pragma unroll
        for (int j = 0; j < 4; j++)
            acc[i][j] = f32x4{0.f, 0.f, 0.f, 0.f};

    const int nkt = K / GBK;

#define LOADT(kt_) do {                                                       \
    const int ko_ = (kt_) * GBK;                                              \
    _Pragma("unroll")                                                         \
    for (int q_ = 0; q_ < 4; q_++) {                                          \
        ra[q_][0] = *(const float4*)(pA[q_] + ko_);                           \
        ra[q_][1] = *(const float4*)(pA[q_] + ko_ + 4);                       \
        rb[q_][0] = *(const float4*)(pB[q_] + ko_);                           \
        rb[q_][1] = *(const float4*)(pB[q_] + ko_ + 4);                       \
    }                                                                         \
} while (0)

#define WRITET(buf_) do {                                                     \
    uint16_t* bA_ = lds + (buf_) * (2 * GBM * GBK) + dst0;                    \
    uint16_t* bB_ = bA_ + GBM * GBK;                                          \
    _Pragma("unroll")                                                         \
    for (int q_ = 0; q_ < 4; q_++) {                                          \
        uint4 oa_, ob_;                                                       \
        oa_.x = cvtpk(ra[q_][0].x, ra[q_][0].y);                              \
        oa_.y = cvtpk(ra[q_][0].z, ra[q_][0].w);                              \
        oa_.z = cvtpk(ra[q_][1].x, ra[q_][1].y);                              \
        oa_.w = cvtpk(ra[q_][1].z, ra[q_][1].w);                              \
        *(uint4*)(bA_ + q_ * 4096) = oa_;                                     \
        ob_.x = cvtpk(rb[q_][0].x, rb[q_][0].y);                              \
        ob_.y = cvtpk(rb[q_][0].z, rb[q_][0].w);                              \
        ob_.z = cvtpk(rb[q_][1].x, rb[q_][1].y);                              \
        ob_.w = cvtpk(rb[q_][1].z, rb[q_][1].w);                              \
        *(uint4*)(bB_ + q_ * 4096) = ob_;                                     \
    }                                                                         \
} while (0)

    // prologue: stage tile 0 into buf0, issue loads for tile 1
    LOADT(0);
    WRITET(0);
    if (nkt > 1) LOADT(1);
    asm volatile("s_waitcnt lgkmcnt(0)" ::: "memory");
    __builtin_amdgcn_sched_barrier(0);
    __builtin_amdgcn_s_barrier();
    asm volatile("" ::: "memory");
    __builtin_amdgcn_sched_barrier(0);

    for (int kt = 0; kt < nkt; ++kt) {
        const int cur = kt & 1;

        // stage first (program order), no fence before compute: scheduler is free
        // to interleave cvt/ds_write/load-issue with the MFMA stream below.
        if (kt + 1 < nkt) {
            WRITET(cur ^ 1);                 // tile kt+1 (regs loaded 1 iter ago)
            if (kt + 2 < nkt) LOADT(kt + 2); // in flight across next barrier
        }

        const uint16_t* A = lds + cur * (2 * GBM * GBK);
        const uint16_t* B = A + GBM * GBK;

        #pragma unroll
        for (int h = 0; h < 2; ++h) {
            const int cN = h ? c1 : c0;
            bf16x8 bfr[4];
            #pragma unroll
            for (int j = 0; j < 4; ++j)
                bfr[j] = *(const bf16x8*)(B + brow0 + j * (16 * GBK) + cN);
            #pragma unroll
            for (int mh = 0; mh < 2; ++mh) {
                bf16x8 afr[4];
                #pragma unroll
                for (int i = 0; i < 4; ++i)
                    afr[i] = *(const bf16x8*)(A + arow0 + mh * (64 * GBK) + i * (16 * GBK) + cN);
                __builtin_amdgcn_s_setprio(1);   // T5
                #pragma unroll
                for (int i = 0; i < 4; ++i)
                    #pragma unroll
                    for (int j = 0; j < 4; ++j)
                        acc[mh * 4 + i][j] = __builtin_amdgcn_mfma_f32_16x16x32_bf16(
                            afr[i], bfr[j], acc[mh * 4 + i][j], 0, 0, 0);
                __builtin_amdgcn_s_setprio(0);
            }
        }

        if (kt + 1 < nkt) {
            asm volatile("s_waitcnt lgkmcnt(0)" ::: "memory");  // ds_writes retired
            __builtin_amdgcn_sched_barrier(0);
            __builtin_amdgcn_s_barrier();                       // buf[cur^1] visible
            asm volatile("" ::: "memory");
            __builtin_amdgcn_sched_barrier(0);
        }
    }
#undef LOADT
#undef WRITET

    // epilogue: C/D layout col=lane&15, row=(lane>>4)*4+reg (m89-verified)
    const int D2 = 2 * D;
    const int mbase = tile_m * GBM + wr * 128 + fc4 * 4;
    const int nbase = tile_n * GBN + wc * 64 + fr;
    #pragma unroll
    for (int ai = 0; ai < 8; ++ai) {
        #pragma unroll
        for (int r = 0; r < 4; ++r) {
            const int token = mbase + ai * 16 + r;
            const int slot  = slots[token];
            if (slot < 0 || slot >= num_slots) continue;
            int p = positions[token];
            p = (CR & (CR - 1)) ? (p % CR) : (p & (CR - 1));
            const float* aperow = ape + (size_t)p * D;
            float* orow = out + (size_t)slot * D2;
            #pragma unroll
            for (int j = 0; j < 4; ++j) {
                const int col = nbase + j * 16;
                float v = acc[ai][j][r];
                if (col >= D) v += aperow[col - D];
                orow[col] = v;
            }
        }
    }

    // fused cache copy: rows not touched by the scatter (flags==0)
    float4* out4 = (float4*)out;
    const int rowlen4 = D2 >> 2;
    if ((rowlen4 & (rowlen4 - 1)) == 0) {
        int sh = 0;
        while ((1 << sh) < rowlen4) ++sh;
        const long total4 = (long)num_slots << sh;
        for (long i = (long)blockIdx.x * GNT + t; i < total4; i += (long)gridDim.x * GNT)
            if (!flags[i >> sh]) out4[i] = cache4[i];
    } else {
        for (int s = blockIdx.x; s < num_slots; s += gridDim.x) {
            if (flags[s]) continue;
            const float4* src = cache4 + (size_t)s * rowlen4;
            float4* dst = out4 + (size_t)s * rowlen4;
            for (int j = t; j < rowlen4; j += GNT) dst[j] = src[j];
        }
    }
}

// ---------------- fallback prep: cache copy (skip overwritten) + cvt x + cvt W ----
__global__ void prep(const float4* __restrict__ cache, float4* __restrict__ out,
                     const uint8_t* __restrict__ flags,
                     const float4* __restrict__ x, uint4* __restrict__ xb,
                     const float4* __restrict__ w, uint4* __restrict__ wb,
                     int n_c4, int nx8, int nw8) {
    const int i = blockIdx.x * blockDim.x + threadIdx.x;
    if (i < n_c4) {
        if (!flags[i >> 8]) out[i] = cache[i];
    } else if (i < n_c4 + nx8) {
        const int j = i - n_c4;
        const float4 a = x[2 * j];
        const float4 b = x[2 * j + 1];
        uint4 o;
        o.x = pack_bf16x2(a.x, a.y);
        o.y = pack_bf16x2(a.z, a.w);
        o.z = pack_bf16x2(b.x, b.y);
        o.w = pack_bf16x2(b.z, b.w);
        xb[j] = o;
    } else if (i < n_c4 + nx8 + nw8) {
        const int j = i - n_c4 - nx8;
        const float4 a = w[2 * j];
        const float4 b = w[2 * j + 1];
        uint4 o;
        o.x = pack_bf16x2(a.x, a.y);
        o.y = pack_bf16x2(a.z, a.w);
        o.z = pack_bf16x2(b.x, b.y);
        o.w = pack_bf16x2(b.z, b.w);
        wb[j] = o;
    }
}

// ---------------- fallback 128x128 bf16 GEMM (non-divisible shapes) ----------
__global__ __launch_bounds__(NT, 4)
void gemm_bf16_scatter(const uint16_t* __restrict__ XB, const uint16_t* __restrict__ WB,
                       const float* __restrict__ ape, const int* __restrict__ positions,
                       const int* __restrict__ slots, float* __restrict__ out,
                       int K, int D, int CR, int num_slots, int n_tiles_m)
{
    __shared__ uint16_t ldsA[BM * BK];
    __shared__ uint16_t ldsB[BN * BK];

    const int tile_m = blockIdx.x % n_tiles_m;
    const int tile_n = blockIdx.x / n_tiles_m;
    const int t    = threadIdx.x;
    const int lane = t & 63;
    const int wid  = t >> 6;
    const int wm   = (wid >> 1) * 64;
    const int wn   = (wid & 1) * 64;
    const int fr   = lane & 15;
    const int fc   = lane >> 4;
    const int swz  = (fc ^ ((fr >> 1) & 3)) << 3;

    const int p0 = t, p1 = t + NT;
    const int r0 = p0 >> 2, cc0 = (p0 & 3) ^ ((r0 >> 1) & 3);
    const int r1 = p1 >> 2, cc1 = (p1 & 3) ^ ((r1 >> 1) & 3);

    const uint16_t* gA0 = XB + (size_t)(tile_m * BM + r0) * K + cc0 * 8;
    const uint16_t* gA1 = XB + (size_t)(tile_m * BM + r1) * K + cc1 * 8;
    const uint16_t* gB0 = WB + (size_t)(tile_n * BN + r0) * K + cc0 * 8;
    const uint16_t* gB1 = WB + (size_t)(tile_n * BN + r1) * K + cc1 * 8;
    uint16_t* lA0 = &ldsA[p0 * 8];
    uint16_t* lA1 = &ldsA[p1 * 8];
    uint16_t* lB0 = &ldsB[p0 * 8];
    uint16_t* lB1 = &ldsB[p1 * 8];

    f32x4 acc[4][4];
    #pragma unroll
    for (int i = 0; i < 4; i++)
        #pragma unroll
        for (int j = 0; j < 4; j++)
            acc[i][j] = f32x4{0.f, 0.f, 0.f, 0.f};

    for (int k0 = 0; k0 < K; k0 += BK) {
        gload_lds16(gA0 + k0, lA0);
        gload_lds16(gA1 + k0, lA1);
        gload_lds16(gB0 + k0, lB0);
        gload_lds16(gB1 + k0, lB1);
        __syncthreads();

        bf16x8 af[4], bfrag[4];
        #pragma unroll
        for (int i = 0; i < 4; i++)
            af[i] = *(const bf16x8*)&ldsA[(wm + i * 16 + fr) * BK + swz];
        #pragma unroll
        for (int j = 0; j < 4; j++)
            bfrag[j] = *(const bf16x8*)&ldsB[(wn + j * 16 + fr) * BK + swz];

        #pragma unroll
        for (int i = 0; i < 4; i++)
            #pragma unroll
            for (int j = 0; j < 4; j++)
                acc[i][j] = __builtin_amdgcn_mfma_f32_16x16x32_bf16(af[i], bfrag[j], acc[i][j], 0, 0, 0);
        __syncthreads();
    }

    const int D2 = 2 * D;
    #pragma unroll
    for (int i = 0; i < 4; i++) {
        #pragma unroll
        for (int r = 0; r < 4; r++) {
            const int token = tile_m * BM + wm + i * 16 + fc * 4 + r;
            const int slot  = slots[token];
            if (slot < 0 || slot >= num_slots) continue;
            const int p = positions[token] % CR;
            const float* aperow = ape + (size_t)p * D;
            float* orow = out + (size_t)slot * D2;
            #pragma unroll
            for (int j = 0; j < 4; j++) {
                const int col = tile_n * BN + wn + j * 16 + fr;
                float v = acc[i][j][r];
                if (col >= D) v += aperow[col - D];
                orow[col] = v;
            }
        }
    }
}

// ---------------- fallback (ws too small): round-1 fp32-staging GEMM ----------------
__global__ void copy_cache(const float4* __restrict__ src, float4* __restrict__ dst, int n4) {
    const int i = blockIdx.x * blockDim.x + threadIdx.x;
    if (i < n4) dst[i] = src[i];
}

__device__ __forceinline__ int lds_idx_f(int row, int chunk) {
    return row * BK + ((chunk ^ ((row >> 1) & 3)) << 3);
}

__global__ __launch_bounds__(NT, 2)
void gemm_scatter_f32(const float* __restrict__ X, const float* __restrict__ Wm,
                      const float* __restrict__ ape, const int* __restrict__ positions,
                      const int* __restrict__ slots, float* __restrict__ out,
                      int K, int D, int CR, int num_slots, int n_tiles_n)
{
    __shared__ uint16_t ldsA[BM * BK];
    __shared__ uint16_t ldsB[BN * BK];

    const int tile_m = blockIdx.x / n_tiles_n;
    const int tile_n = blockIdx.x % n_tiles_n;
    const int t    = threadIdx.x;
    const int lane = t & 63;
    const int wid  = t >> 6;
    const int wm   = (wid >> 1) * 64;
    const int wn   = (wid & 1) * 64;
    const int fr   = lane & 15;
    const int fc   = lane >> 4;
    const int swz  = fc ^ ((fr >> 1) & 3);

    const float* Abase = X  + (size_t)(tile_m * BM) * K;
    const float* Bbase = Wm + (size_t)(tile_n * BN) * K;

    f32x4 acc[4][4];
    #pragma unroll
    for (int i = 0; i < 4; i++)
        #pragma unroll
        for (int j = 0; j < 4; j++)
            acc[i][j] = f32x4{0.f, 0.f, 0.f, 0.f};

    for (int k0 = 0; k0 < K; k0 += BK) {
        #pragma unroll
        for (int i = 0; i < 4; i++) {
            const int lin = t + i * NT;
            const int row = lin >> 3;
            const int c4  = lin & 7;
            const int half = c4 & 1;
            const int sidx = lds_idx_f(row, c4 >> 1) + half * 4;

            const float4 va = *(const float4*)(Abase + (size_t)row * K + k0 + c4 * 4);
            uint2 pa; pa.x = pack_bf16x2(va.x, va.y); pa.y = pack_bf16x2(va.z, va.w);
            *(uint2*)&ldsA[sidx] = pa;

            const float4 vb = *(const float4*)(Bbase + (size_t)row * K + k0 + c4 * 4);
            uint2 pb; pb.x = pack_bf16x2(vb.x, vb.y); pb.y = pack_bf16x2(vb.z, vb.w);
            *(uint2*)&ldsB[sidx] = pb;
        }
        __syncthreads();

        bf16x8 af[4], bfrag[4];
        #pragma unroll
        for (int i = 0; i < 4; i++)
            af[i] = *(const bf16x8*)&ldsA[(wm + i * 16 + fr) * BK + (swz << 3)];
        #pragma unroll
        for (int j = 0; j < 4; j++)
            bfrag[j] = *(const bf16x8*)&ldsB[(wn + j * 16 + fr) * BK + (swz << 3)];

        #pragma unroll
        for (int i = 0; i < 4; i++)
            #pragma unroll
            for (int j = 0; j < 4; j++)
                acc[i][j] = __builtin_amdgcn_mfma_f32_16x16x32_bf16(af[i], bfrag[j], acc[i][j], 0, 0, 0);
        __syncthreads();
    }

    const int D2 = 2 * D;
    #pragma unroll
    for (int i = 0; i < 4; i++) {
        #pragma unroll
        for (int r = 0; r < 4; r++) {
            const int token = tile_m * BM + wm + i * 16 + fc * 4 + r;
            const int slot  = slots[token];
            if (slot < 0 || slot >= num_slots) continue;
            const int p = positions[token] % CR;
            const float* aperow = ape + (size_t)p * D;
            float* orow = out + (size_t)slot * D2;
            #pragma unroll
            for (int j = 0; j < 4; j++) {
                const int col = tile_n * BN + wn + j * 16 + fr;
                float v = acc[i][j][r];
                if (col >= D) v += aperow[col - D];
                orow[col] = v;
            }
        }
    }
}

extern "C" void kernel_launch(void* const* d_in, const int* in_sizes, int n_in,
                              void* d_out, int out_size, void* d_ws, size_t ws_size,
                              hipStream_t stream) {
    const float* x         = (const float*)d_in[0];
    const float* W         = (const float*)d_in[1];
    const float* ape       = (const float*)d_in[2];
    const float* cache     = (const float*)d_in[3];
    const int*   positions = (const int*)d_in[4];
    const int*   slots     = (const int*)d_in[5];
    float* out = (float*)d_out;

    const int num_tokens = in_sizes[4];
    const int hidden     = in_sizes[0] / num_tokens;   // 7168
    const int D2         = in_sizes[1] / hidden;       // 1024
    const int D          = D2 / 2;                     // 512
    const int CR         = in_sizes[2] / D;            // 128
    const int num_slots  = in_sizes[3] / D2;           // 32768

    const int n_tiles_m = num_tokens / BM;   // 128
    const int n_tiles_n = D2 / BN;           // 8

    const size_t nx = (size_t)in_sizes[0];
    const size_t nw = (size_t)in_sizes[1];
    const size_t need_old = (nx + nw) * sizeof(uint16_t) + (size_t)num_slots;

    const bool div256 = (num_tokens % GBM == 0) && (D2 % GBN == 0) && (hidden % GBK == 0);

    if (div256 && ws_size >= (size_t)num_slots) {
        // main path: memset(flags) + set_flags + single fused GEMM kernel
        uint8_t* flags = (uint8_t*)d_ws;
        hipMemsetAsync(flags, 0, num_slots, stream);
        set_flags<<<(num_tokens + 255) / 256, 256, 0, stream>>>(slots, flags, num_tokens, num_slots);

        const int tm = num_tokens / GBM;   // 64
        const int tn = D2 / GBN;           // 4
        gemm_fused2_256<<<tm * tn, GNT, 0, stream>>>(
            x, W, ape, positions, slots, (const float4*)cache, flags, out,
            hidden, D, CR, num_slots, tm, tn);
    } else if (ws_size >= need_old) {
        uint16_t* xb = (uint16_t*)d_ws;
        uint16_t* wb = xb + nx;
        uint8_t* flags = (uint8_t*)(wb + nw);

        hipMemsetAsync(flags, 0, num_slots, stream);
        set_flags<<<(num_tokens + 255) / 256, 256, 0, stream>>>(slots, flags, num_tokens, num_slots);

        const int n_c4 = out_size / 4;
        const int nx8  = (int)(nx / 8);
        const int nw8  = (int)(nw / 8);
        const int total = n_c4 + nx8 + nw8;
        prep<<<(total + 255) / 256, 256, 0, stream>>>(
            (const float4*)cache, (float4*)out, flags,
            (const float4*)x, (uint4*)xb, (const float4*)W, (uint4*)wb,
            n_c4, nx8, nw8);

        gemm_bf16_scatter<<<n_tiles_m * n_tiles_n, NT, 0, stream>>>(
            xb, wb, ape, positions, slots, out, hidden, D, CR, num_slots, n_tiles_m);
    } else {
        const int n4 = out_size / 4;
        copy_cache<<<(n4 + 255) / 256, 256, 0, stream>>>((const float4*)cache, (float4*)out, n4);
        gemm_scatter_f32<<<n_tiles_m * n_tiles_n, NT, 0, stream>>>(
            x, W, ape, positions, slots, out, hidden, D, CR, num_slots, n_tiles_n);
    }
}